// Round 5
// 350.475 us; speedup vs baseline: 1.0179x; 1.0179x over previous
//
#include <hip/hip_runtime.h>
#include <hip/hip_bf16.h>

// DQNNetwork: M=65536, K=768, N=512 hidden, 3 actions. All I/O fp32.
//   h = relu(X @ Wh^T + bh)
//   d1[i,a] = dot(h[i], Wf[a,0:512]);  d2[i,a] = dot(h[i], Wf[a,512:1024])
//   out[i,a] = relu( d1 - d2/(M-1) + bf[a] + (sum_i d2[i,a])/(M-1) )
// R8 (resubmit x4 — GPU-broker timeouts, kernel never measured):
// double-buffered 2-phase pipeline (T3-minimum + T14).
//   A (X fp32) is REG-STAGED: float4 global loads issued before the current
//   tile's MFMAs, cvt_pk->bf16 + swizzled ds_write after them (R5-verified
//   write pattern, 0 bank conflicts). B (Whb bf16) stays DMA (global_load_lds).
//   One barrier per K-step; stage latency hides under compute.
//   LDS 4x16KB = 64KB -> 2 blocks/CU; VGPR budget 256/wave (no spill).
// Wh pre-converted to bf16 by a tiny kernel (0.75 MB).

#define M_DIM 65536
#define K_DIM 768
#define N_DIM 512
#define INV_NM1 (1.0f / 65535.0f)
#define OUT_ELEMS (M_DIM * 3)

typedef __attribute__((ext_vector_type(8))) short shortx8;   // 8 bf16 (4 VGPRs)
typedef __attribute__((ext_vector_type(4))) float floatx4;   // MFMA C/D
typedef __attribute__((ext_vector_type(4))) unsigned int uintx4;

__device__ __forceinline__ unsigned short f2b(float f) {
    unsigned u = __float_as_uint(f);
    unsigned r = (u + 0x7fffu + ((u >> 16) & 1u)) >> 16;   // RNE
    return (unsigned short)r;
}

#if defined(__has_builtin)
#  if __has_builtin(__builtin_amdgcn_cvt_pk_bf16_f32)
#    define HAVE_CVT_PK_BF16 1
#  endif
#endif

__device__ __forceinline__ unsigned pack2bf(float x, float y) {   // {x->lo, y->hi}, HW-verified R6
#ifdef HAVE_CVT_PK_BF16
    typedef __attribute__((ext_vector_type(2))) __bf16 bf16x2_t;
    bf16x2_t t = __builtin_amdgcn_cvt_pk_bf16_f32(x, y);
    return __builtin_bit_cast(unsigned, t);
#else
    return (unsigned)f2b(x) | ((unsigned)f2b(y) << 16);
#endif
}

// async global->LDS DMA, 16B/lane; deposits at (wave-uniform base) + lane*16.
__device__ __forceinline__ void async16(const void* g, void* l) {
    __builtin_amdgcn_global_load_lds(
        (const __attribute__((address_space(1))) void*)g,
        (__attribute__((address_space(3))) void*)l,
        16, 0, 0);
}

// ---------------------------------------------------------------------------
// Streaming fp32 -> bf16 convert (used for Wh only, 0.75 MB).
// ---------------------------------------------------------------------------
__global__ __launch_bounds__(256) void cvt_bf16_kernel(
    const float* __restrict__ src, unsigned short* __restrict__ dst, int n8)
{
    const int idx = blockIdx.x * 256 + threadIdx.x;
    if (idx >= n8) return;
    const float4 a = *(const float4*)(src + (size_t)idx * 8);
    const float4 b = *(const float4*)(src + (size_t)idx * 8 + 4);
    uint4 o;
    o.x = pack2bf(a.x, a.y); o.y = pack2bf(a.z, a.w);
    o.z = pack2bf(b.x, b.y); o.w = pack2bf(b.z, b.w);
    *(uint4*)(dst + (size_t)idx * 8) = o;
}

// ---------------------------------------------------------------------------
// Fused GEMM + head. 128x128 tile, 4 waves (2x2 of 64x64), BK=64, 16x16x32.
// Double-buffered (R8):
//   per step t: issue A float4 loads(t+1) + B DMA(t+1) -> compute(t) from
//   buf[cur] -> cvt+ds_write A(t+1) into buf[nxt] -> ONE __syncthreads().
//   The barrier's vmcnt(0)/lgkmcnt(0) drain lands AFTER compute, so the
//   global latency is hidden inside the block (2 blocks/CU is enough).
// A LDS layout (bf16): 16B chunk j of row r at slot j^(r&7)  (R5-verified).
// B LDS layout (bf16): same involution, filled by pre-swizzled DMA source.
// Frag reads: single ds_read_b128, 2 lanes/bank-group -> conflict-free.
// Block swizzle: 4 n-slots of an m-tile -> same XCD (R4-R6: FETCH 399->128MB).
// ---------------------------------------------------------------------------
__global__ __launch_bounds__(256, 2) void gemm_fused_kernel(
    const float* __restrict__ X,              // [M,K] fp32
    const unsigned short* __restrict__ Whb,   // [N,K] bf16
    const float* __restrict__ bh,             // [N]
    const float* __restrict__ Wf,             // [3,1024]
    float* __restrict__ gsum,                 // [3], pre-zeroed
    float* __restrict__ pslice)               // [8][M*3], each elem written once
{
    __shared__ unsigned short As[2][128 * 64];  // 2 x 16 KB bf16
    __shared__ unsigned short Bs[2][128 * 64];  // 2 x 16 KB bf16  (total 64 KB)

    const int tid  = threadIdx.x;
    const int wave = tid >> 6;
    const int lane = tid & 63;
    const int l16  = lane & 15;
    const int quad = lane >> 4;
    const int wm   = wave >> 1;
    const int wn   = wave & 1;
    const int swr  = l16 & 7;

    // XCD-aware swizzle: b = g*32 + slot*8 + xcd; m-tile = g*8+xcd, n = slot.
    const int b  = blockIdx.x;
    const int g  = b >> 5;
    const int r  = b & 31;
    const int m0 = (g * 8 + (r & 7)) * 128;
    const int n0 = (r >> 3) * 128;

    floatx4 acc[4][4];
    #pragma unroll
    for (int i = 0; i < 4; i++)
        #pragma unroll
        for (int j = 0; j < 4; j++) {
            floatx4 z = {0.f, 0.f, 0.f, 0.f};
            acc[i][j] = z;
        }

    // A reg-staging mapping: thread handles rows {u, u+16, ..., u+112},
    // float4 chunk q of each. bf16 dest chunk jc=q>>1 at slot jc^(row&7);
    // row&7 == u&7 since the p-stride (16 rows) is a multiple of 8.
    const int u    = tid >> 4;           // 0..15
    const int q    = tid & 15;           // float4 col index
    const int aoff = u * 64 + (((q >> 1) ^ (u & 7)) << 3) + ((q & 1) << 2);
    const float* xb = X + (size_t)(m0 + u) * K_DIM + q * 4;

    // B DMA lane mapping: 1KB issue = 8 bf16 rows.
    const int uB = lane >> 3, sBch = lane & 7;

    float4 av[8];

    // ---- prologue: stage tile 0 ----
    #pragma unroll
    for (int p = 0; p < 8; p++)
        av[p] = *(const float4*)(xb + (size_t)p * 16 * K_DIM);
    #pragma unroll
    for (int it = 0; it < 4; it++) {
        const int j   = wave * 4 + it;
        const int r0  = j * 8;
        const int row = r0 + uB;
        const int gch = sBch ^ (row & 7);
        async16(Whb + (size_t)(n0 + row) * K_DIM + gch * 8, &Bs[0][r0 * 64]);
    }
    #pragma unroll
    for (int p = 0; p < 8; p++) {
        uint2 o;
        o.x = pack2bf(av[p].x, av[p].y);
        o.y = pack2bf(av[p].z, av[p].w);
        *(uint2*)(&As[0][aoff + p * 1024]) = o;
    }
    __syncthreads();

    // ---- main loop: 12 K-steps, one barrier each ----
    #pragma unroll 2
    for (int t = 0; t < 12; t++) {
        const int cur = t & 1;
        const int nxt = cur ^ 1;
        const int k1  = (t + 1) * 64;
        if (t < 11) {
            // issue next A-tile loads first, then next B-tile DMA.
            #pragma unroll
            for (int p = 0; p < 8; p++)
                av[p] = *(const float4*)(xb + (size_t)p * 16 * K_DIM + k1);
            #pragma unroll
            for (int it = 0; it < 4; it++) {
                const int j   = wave * 4 + it;
                const int r0  = j * 8;
                const int row = r0 + uB;
                const int gch = sBch ^ (row & 7);
                async16(Whb + (size_t)(n0 + row) * K_DIM + k1 + gch * 8,
                        &Bs[nxt][r0 * 64]);
            }
        }

        // compute current tile
        #pragma unroll
        for (int kk = 0; kk < 64; kk += 32) {
            shortx8 afrag[4], bfrag[4];
            const int jq = (kk >> 3) + quad;
            const int co = ((jq ^ swr) << 3);
            #pragma unroll
            for (int mt = 0; mt < 4; mt++)
                afrag[mt] = *(const shortx8*)(&As[cur][(wm * 64 + mt * 16 + l16) * 64 + co]);
            #pragma unroll
            for (int nt = 0; nt < 4; nt++)
                bfrag[nt] = *(const shortx8*)(&Bs[cur][(wn * 64 + nt * 16 + l16) * 64 + co]);
            #pragma unroll
            for (int mt = 0; mt < 4; mt++)
                #pragma unroll
                for (int nt = 0; nt < 4; nt++)
                    acc[mt][nt] = __builtin_amdgcn_mfma_f32_16x16x32_bf16(
                        afrag[mt], bfrag[nt], acc[mt][nt], 0, 0, 0);
        }

        // finish staging A(t+1): cvt + swizzled LDS write
        if (t < 11) {
            #pragma unroll
            for (int p = 0; p < 8; p++) {
                uint2 o;
                o.x = pack2bf(av[p].x, av[p].y);
                o.y = pack2bf(av[p].z, av[p].w);
                *(uint2*)(&As[nxt][aoff + p * 1024]) = o;
            }
        }
        __syncthreads();
    }

    // ---- Epilogue. C/D layout: col = lane&15, row = quad*4 + reg. ----
    float bhv[4], wpr0[4], wpr1[4], wpr2[4], w20[4], w21[4], w22[4];
    #pragma unroll
    for (int nt = 0; nt < 4; nt++) {
        const int col = n0 + wn * 64 + nt * 16 + l16;
        bhv[nt] = bh[col];
        w20[nt] = Wf[512 + col];
        w21[nt] = Wf[1536 + col];
        w22[nt] = Wf[2560 + col];
        wpr0[nt] = Wf[col]        - w20[nt] * INV_NM1;
        wpr1[nt] = Wf[1024 + col] - w21[nt] * INV_NM1;
        wpr2[nt] = Wf[2048 + col] - w22[nt] * INV_NM1;
    }

    float* ps = pslice + (size_t)((r >> 3) * 2 + wn) * OUT_ELEMS;

    float q0 = 0.f, q1 = 0.f, q2 = 0.f;   // partials of sum_i d2[i,a]
    #pragma unroll
    for (int mt = 0; mt < 4; mt++) {
        #pragma unroll
        for (int rg = 0; rg < 4; rg++) {
            float p0 = 0.f, p1 = 0.f, p2 = 0.f;
            #pragma unroll
            for (int nt = 0; nt < 4; nt++) {
                float v = acc[mt][nt][rg] + bhv[nt];
                v = v > 0.f ? v : 0.f;
                p0 += v * wpr0[nt];
                p1 += v * wpr1[nt];
                p2 += v * wpr2[nt];
                q0 += v * w20[nt];
                q1 += v * w21[nt];
                q2 += v * w22[nt];
            }
            #pragma unroll
            for (int off = 1; off < 16; off <<= 1) {
                p0 += __shfl_xor(p0, off, 64);
                p1 += __shfl_xor(p1, off, 64);
                p2 += __shfl_xor(p2, off, 64);
            }
            if (l16 == 0) {
                const int row = m0 + wm * 64 + mt * 16 + quad * 4 + rg;
                ps[row * 3 + 0] = p0;
                ps[row * 3 + 1] = p1;
                ps[row * 3 + 2] = p2;
            }
        }
    }
    #pragma unroll
    for (int off = 1; off < 64; off <<= 1) {
        q0 += __shfl_xor(q0, off, 64);
        q1 += __shfl_xor(q1, off, 64);
        q2 += __shfl_xor(q2, off, 64);
    }
    float* red = (float*)As;   // reuse LDS for the 48B block reduction
    if (lane == 0) { red[wave * 3 + 0] = q0; red[wave * 3 + 1] = q1; red[wave * 3 + 2] = q2; }
    __syncthreads();
    if (tid < 3)
        atomicAdd(&gsum[tid], red[tid] + red[3 + tid] + red[6 + tid] + red[9 + tid]);
}

// ---------------------------------------------------------------------------
// finalize: out[idx] = relu( sum_s pslice[s][idx] + gsum[a]*INV + bf[a] )
// ---------------------------------------------------------------------------
__global__ __launch_bounds__(256) void finalize_kernel(
    const float* __restrict__ pslice, const float* __restrict__ gsum,
    const float* __restrict__ bfb, float* __restrict__ out)
{
    const int idx = blockIdx.x * 256 + threadIdx.x;
    float s = 0.f;
    #pragma unroll
    for (int sl = 0; sl < 8; sl++)
        s += pslice[(size_t)sl * OUT_ELEMS + idx];
    const int a = idx % 3;
    const float v = s + gsum[a] * INV_NM1 + bfb[a];
    out[idx] = v > 0.f ? v : 0.f;
}

// ---------------------------------------------------------------------------
// Fallback (R5 path, HW-verified): fused fp32 register-staging GEMM.
// ---------------------------------------------------------------------------
__global__ __launch_bounds__(256) void gemm_fused_fp32_kernel(
    const float* __restrict__ X, const float* __restrict__ Wh,
    const float* __restrict__ bh, const float* __restrict__ Wf,
    float* __restrict__ gsum, float* __restrict__ pslice)
{
    __shared__ unsigned short As[128 * 64];
    __shared__ unsigned short Bs[128 * 64];

    const int tid  = threadIdx.x;
    const int wave = tid >> 6;
    const int lane = tid & 63;
    const int l16  = lane & 15;
    const int quad = lane >> 4;
    const int wm   = wave >> 1;
    const int wn   = wave & 1;

    const int b  = blockIdx.x;
    const int g  = b >> 5;
    const int r  = b & 31;
    const int m0 = (g * 8 + (r & 7)) * 128;
    const int n0 = (r >> 3) * 128;

    floatx4 acc[4][4];
    #pragma unroll
    for (int i = 0; i < 4; i++)
        #pragma unroll
        for (int j = 0; j < 4; j++) {
            floatx4 z = {0.f, 0.f, 0.f, 0.f};
            acc[i][j] = z;
        }

    const int swr = l16 & 7;

    for (int k0 = 0; k0 < K_DIM; k0 += 64) {
        #pragma unroll
        for (int p = 0; p < 8; p++) {
            const int c   = p * 256 + tid;
            const int row = c >> 4;
            const int q   = c & 15;
            const int f4  = q << 2;
            const int jch = q >> 1;
            const int off = row * 64 + ((jch ^ (row & 7)) << 3) + ((q & 1) << 2);
            const float4 av = *(const float4*)(X  + (size_t)(m0 + row) * K_DIM + k0 + f4);
            const float4 bv = *(const float4*)(Wh + (size_t)(n0 + row) * K_DIM + k0 + f4);
            uint2 a2, b2;
            a2.x = pack2bf(av.x, av.y); a2.y = pack2bf(av.z, av.w);
            b2.x = pack2bf(bv.x, bv.y); b2.y = pack2bf(bv.z, bv.w);
            *(uint2*)(As + off) = a2;
            *(uint2*)(Bs + off) = b2;
        }
        __syncthreads();

        #pragma unroll
        for (int kk = 0; kk < 64; kk += 32) {
            shortx8 afrag[4], bfrag[4];
            const int jq = (kk >> 3) + quad;
            const int co = ((jq ^ swr) << 3);
            #pragma unroll
            for (int mt = 0; mt < 4; mt++)
                afrag[mt] = *(const shortx8*)(As + (wm * 64 + mt * 16 + l16) * 64 + co);
            #pragma unroll
            for (int nt = 0; nt < 4; nt++)
                bfrag[nt] = *(const shortx8*)(Bs + (wn * 64 + nt * 16 + l16) * 64 + co);
            #pragma unroll
            for (int mt = 0; mt < 4; mt++)
                #pragma unroll
                for (int nt = 0; nt < 4; nt++)
                    acc[mt][nt] = __builtin_amdgcn_mfma_f32_16x16x32_bf16(
                        afrag[mt], bfrag[nt], acc[mt][nt], 0, 0, 0);
        }
        __syncthreads();
    }

    float bhv[4], wpr0[4], wpr1[4], wpr2[4], w20[4], w21[4], w22[4];
    #pragma unroll
    for (int nt = 0; nt < 4; nt++) {
        const int col = n0 + wn * 64 + nt * 16 + l16;
        bhv[nt] = bh[col];
        w20[nt] = Wf[512 + col];
        w21[nt] = Wf[1536 + col];
        w22[nt] = Wf[2560 + col];
        wpr0[nt] = Wf[col]        - w20[nt] * INV_NM1;
        wpr1[nt] = Wf[1024 + col] - w21[nt] * INV_NM1;
        wpr2[nt] = Wf[2048 + col] - w22[nt] * INV_NM1;
    }

    float* ps = pslice + (size_t)((r >> 3) * 2 + wn) * OUT_ELEMS;

    float q0 = 0.f, q1 = 0.f, q2 = 0.f;
    #pragma unroll
    for (int mt = 0; mt < 4; mt++) {
        #pragma unroll
        for (int rg = 0; rg < 4; rg++) {
            float p0 = 0.f, p1 = 0.f, p2 = 0.f;
            #pragma unroll
            for (int nt = 0; nt < 4; nt++) {
                float v = acc[mt][nt][rg] + bhv[nt];
                v = v > 0.f ? v : 0.f;
                p0 += v * wpr0[nt];
                p1 += v * wpr1[nt];
                p2 += v * wpr2[nt];
                q0 += v * w20[nt];
                q1 += v * w21[nt];
                q2 += v * w22[nt];
            }
            #pragma unroll
            for (int off = 1; off < 16; off <<= 1) {
                p0 += __shfl_xor(p0, off, 64);
                p1 += __shfl_xor(p1, off, 64);
                p2 += __shfl_xor(p2, off, 64);
            }
            if (l16 == 0) {
                const int row = m0 + wm * 64 + mt * 16 + quad * 4 + rg;
                ps[row * 3 + 0] = p0;
                ps[row * 3 + 1] = p1;
                ps[row * 3 + 2] = p2;
            }
        }
    }
    #pragma unroll
    for (int off = 1; off < 64; off <<= 1) {
        q0 += __shfl_xor(q0, off, 64);
        q1 += __shfl_xor(q1, off, 64);
        q2 += __shfl_xor(q2, off, 64);
    }
    float* red = (float*)As;
    if (lane == 0) { red[wave * 3 + 0] = q0; red[wave * 3 + 1] = q1; red[wave * 3 + 2] = q2; }
    __syncthreads();
    if (tid < 3)
        atomicAdd(&gsum[tid], red[tid] + red[3 + tid] + red[6 + tid] + red[9 + tid]);
}

extern "C" void kernel_launch(void* const* d_in, const int* in_sizes, int n_in,
                              void* d_out, int out_size, void* d_ws, size_t ws_size,
                              hipStream_t stream) {
    const float* X   = (const float*)d_in[0];
    const float* Wh  = (const float*)d_in[1];
    const float* bh  = (const float*)d_in[2];
    const float* Wf  = (const float*)d_in[3];
    const float* bfb = (const float*)d_in[4];
    for (int i = 0; i < n_in; i++) {
        const float* p = (const float*)d_in[i];
        switch (in_sizes[i]) {
            case M_DIM * K_DIM: X   = p; break;
            case N_DIM * K_DIM: Wh  = p; break;
            case N_DIM:         bh  = p; break;
            case 3 * 2 * N_DIM: Wf  = p; break;
            case 3:             bfb = p; break;
            default: break;
        }
    }
    float* out = (float*)d_out;

    // ws layout: [gsum 2048][pslice 6.29MB][Whb 0.75MB]
    char* w = (char*)d_ws;
    float*          gsum   = (float*)w;
    float*          pslice = (float*)(w + 2048);
    unsigned short* Whb    = (unsigned short*)(w + 2048 + (size_t)8 * OUT_ELEMS * 4);
    const size_t need = 2048 + (size_t)8 * OUT_ELEMS * 4 + (size_t)N_DIM * K_DIM * 2;

    hipMemsetAsync(gsum, 0, 2048, stream);

    if (ws_size >= need) {
        cvt_bf16_kernel<<<(N_DIM * K_DIM / 8) / 256, 256, 0, stream>>>(Wh, Whb, N_DIM * K_DIM / 8);
        gemm_fused_kernel<<<2048, 256, 0, stream>>>(X, Whb, bh, Wf, gsum, pslice);
    } else {
        gemm_fused_fp32_kernel<<<2048, 256, 0, stream>>>(X, Wh, bh, Wf, gsum, pslice);
    }
    finalize_kernel<<<OUT_ELEMS / 256, 256, 0, stream>>>(pslice, gsum, bfb, out);
}